// Round 14
// baseline (120.105 us; speedup 1.0000x reference)
//
#include <hip/hip_runtime.h>
#include <hip/hip_fp16.h>

// ---------------------------------------------------------------------------
// MultiSourceGNNBlock: two independent 2-layer GAT stacks on shared input.
// R14: layer-0 commute trick — attention gathers in h0-space (64 dims, 4x
// less L2 traffic); alpha0 via pre-GEMV h0·(W@a); gemm0 folded into a
// block-diagonal stage fused in front of gemm1 (hb lives only in LDS).
// Layer 1 unchanged (xh-space). 5 dispatches.
// ---------------------------------------------------------------------------

#define NEG_SLOPE 0.2f
#define ELLW 96

typedef _Float16 half8 __attribute__((ext_vector_type(8)));
typedef float floatx4 __attribute__((ext_vector_type(4)));

struct Args {
    const float* h0;
    const int *ei1, *ei2;
    const float *W10, *W11, *W20, *W21;
    const float *as10, *ad10, *b10, *as11, *ad11, *b11;
    const float *as20, *ad20, *b20, *as21, *ad21, *b21;
    _Float16 *Wt10, *Wt20, *Wt11, *Wt21;    // W^T fp16
    float *vaS1, *vaD1, *vaS2, *vaD2;       // [4][64] = W0 @ a_{src,dst}
    _Float16 *h0h;                          // h0 as fp16 [N][64]
    int *cnt, *slots;
    _Float16 *agg1, *agg2;                  // [N][256] layer0 weighted sums
    _Float16 *xh1, *xh2;                    // [N][256] layer1 features
    float *alS1, *alD1, *alS2, *alD2;       // [N][4] (layer0 then layer1)
    float *out0, *out1;
    int N, E1, E2, AB;                      // AB = al0 block count
};

// ---------------- d1: W transposes + va GEMV + h0->fp16 + cnt zero ----------
// grid (256, 5, 2), block 64.

__global__ __launch_bounds__(64) void prep_kernel(Args a) {
    int z = blockIdx.z, y = blockIdx.y, c = blockIdx.x;
    int t = threadIdx.x;
    int flat = ((z * gridDim.y + y) * gridDim.x + c) * 64 + t;
    int GT = gridDim.x * gridDim.y * gridDim.z * 64;
    if (flat < 2 * a.N) a.cnt[flat] = 0;
    for (int i = flat; i < a.N * 64; i += GT)
        a.h0h[i] = (_Float16)a.h0[i];
    if (y == 0) {
        const float* W  = z ? a.W20  : a.W10;
        _Float16*    Wt = z ? a.Wt20 : a.Wt10;
        Wt[(size_t)c * 64 + t] = (_Float16)W[(size_t)t * 256 + c];
        if (c < 8) {            // va: v = c -> (sel = c>>2, h = c&3)
            int h = c & 3, sel = c >> 2;
            const float* av = sel ? (z ? a.ad20 : a.ad10)
                                  : (z ? a.as20 : a.as10);
            float* va = sel ? (z ? a.vaD2 : a.vaD1)
                            : (z ? a.vaS2 : a.vaS1);
            float acc = 0.f;
            for (int cc = 0; cc < 64; cc++)
                acc += W[(size_t)t * 256 + h * 64 + cc] * av[h * 64 + cc];
            va[h * 64 + t] = acc;
        }
    } else {
        int k = (y - 1) * 64 + t;
        const float* W  = z ? a.W21  : a.W11;
        _Float16*    Wt = z ? a.Wt21 : a.Wt11;
        Wt[(size_t)c * 256 + k] = (_Float16)W[(size_t)k * 256 + c];
    }
}

// ---------------- d2: alpha0 GEMV + ELL scatter, one dispatch ---------------
// Blocks [0, AB): one wave per (source,node): alS0/alD0 = h0 . va.
// Blocks [AB, ...): edge scatter.

__global__ __launch_bounds__(256) void scat_al0_kernel(Args a) {
    int b = blockIdx.x;
    int tid = threadIdx.x;
    if (b < a.AB) {
        int g = b * 4 + (tid >> 6);
        if (g >= 2 * a.N) return;
        int L = tid & 63;
        int s = (g >= a.N) ? 1 : 0;
        int i = g - s * a.N;
        const float* vaS = s ? a.vaS2 : a.vaS1;
        const float* vaD = s ? a.vaD2 : a.vaD1;
        float* alS = s ? a.alS2 : a.alS1;
        float* alD = s ? a.alD2 : a.alD1;
        float x = a.h0[(size_t)i * 64 + L];
#pragma unroll
        for (int h = 0; h < 4; h++) {
            float sv = x * vaS[h * 64 + L];
            float dv = x * vaD[h * 64 + L];
#pragma unroll
            for (int off = 32; off >= 1; off >>= 1) {
                sv += __shfl_xor(sv, off);
                dv += __shfl_xor(dv, off);
            }
            if (L == 0) {
                alS[i * 4 + h] = sv;
                alD[i * 4 + h] = dv;
            }
        }
    } else {
        int i = (b - a.AB) * 256 + tid;
        int tot1 = a.E1 + a.N, tot2 = a.E2 + a.N;
        if (i >= tot1 + tot2) return;
        int s, j; const int* ei; int E;
        if (i < tot1) { s = 0; j = i;        ei = a.ei1; E = a.E1; }
        else          { s = 1; j = i - tot1; ei = a.ei2; E = a.E2; }
        int src, dst;
        if (j < E) { src = ei[j]; dst = ei[E + j]; }
        else       { src = dst = j - E; }
        int gg = s * a.N + dst;
        int pos = atomicAdd(&a.cnt[gg], 1);
        if (pos < ELLW) a.slots[(size_t)gg * ELLW + pos] = src;
    }
}

// ---------------- d3: attn0 in h0-space (R8 8-stream ILP + swizzle) ---------
// Gathers 128B h0h rows; writes agg[dst][h*64+cols] (no bias/relu).

__global__ __launch_bounds__(256) void attn_agg_kernel(Args a) {
    __shared__ float2 pairs[4][8][10];
    int tid = threadIdx.x;
    int h = tid >> 6, L = tid & 63, st = L >> 3, lc = L & 7;
    int b = blockIdx.x;
    int cpx = (2 * a.N) >> 3;
    int g = (b & 7) * cpx + (b >> 3);
    int s = (g >= a.N) ? 1 : 0;
    int dst = g - s * a.N;
    const float* alS = s ? a.alS2 : a.alS1;
    const float* alD = s ? a.alD2 : a.alD1;
    _Float16*    agg = s ? a.agg2 : a.agg1;

    const int* slots = a.slots + (size_t)g * ELLW;
    int pre = slots[L];
    int nd = a.cnt[g];
    if (nd > ELLW) nd = ELLW;
    float ad = alD[dst * 4 + h];
    const char* xb = (const char*)a.h0h + lc * 16;   // shared across sources

    float acc[8] = {};
    float pden = 0.f;

    for (int c = 0; c < nd; c += 64) {
        int n = nd - c; if (n > 64) n = 64;
        int off = 0; float p = 0.f;
        if (L < n) {
            int src = (c == 0) ? pre : slots[c + L];
            float t = alS[src * 4 + h] + ad;
            t = (t > 0.f) ? t : NEG_SLOPE * t;
            p = __expf(t);
            off = src * 128;                // 64 fp16 = 128B rows
        }
        pden += p;
        pairs[h][L & 7][L >> 3] = make_float2(__int_as_float(off), p);
        int iters = (n + 7) >> 3;
        for (int ii = 0; ii < iters; ii += 4) {
            float4 twoA = *(const float4*)&pairs[h][st][ii];
            float4 twoB = *(const float4*)&pairs[h][st][ii + 2];
            int   o0 = __float_as_int(twoA.x); float w0 = twoA.y;
            int   o1i = __float_as_int(twoA.z); float w1 = twoA.w;
            int   o2i = __float_as_int(twoB.x); float w2 = twoB.y;
            int   o3i = __float_as_int(twoB.z); float w3 = twoB.w;
            float4 r0 = *(const float4*)(xb + o0);
            float4 r1 = *(const float4*)(xb + o1i);
            float4 r2 = *(const float4*)(xb + o2i);
            float4 r3 = *(const float4*)(xb + o3i);
            const __half2* q0 = (const __half2*)&r0;
            const __half2* q1 = (const __half2*)&r1;
            const __half2* q2 = (const __half2*)&r2;
            const __half2* q3 = (const __half2*)&r3;
#pragma unroll
            for (int k = 0; k < 4; k++) {
                acc[2 * k + 0] += (float)q0[k].x * w0;
                acc[2 * k + 1] += (float)q0[k].y * w0;
                acc[2 * k + 0] += (float)q1[k].x * w1;
                acc[2 * k + 1] += (float)q1[k].y * w1;
                acc[2 * k + 0] += (float)q2[k].x * w2;
                acc[2 * k + 1] += (float)q2[k].y * w2;
                acc[2 * k + 0] += (float)q3[k].x * w3;
                acc[2 * k + 1] += (float)q3[k].y * w3;
            }
        }
    }
#pragma unroll
    for (int k = 0; k < 8; k++) {
        acc[k] += __shfl_xor(acc[k], 8);
        acc[k] += __shfl_xor(acc[k], 16);
        acc[k] += __shfl_xor(acc[k], 32);
    }
#pragma unroll
    for (int o2_ = 32; o2_ >= 1; o2_ >>= 1) pden += __shfl_xor(pden, o2_);

    if (st == 0) {
        float d = 1.0f / (pden + 1e-16f);
        int col = h * 64 + lc * 8;
        half8 ov;
#pragma unroll
        for (int k = 0; k < 8; k++) ov[k] = (_Float16)(acc[k] * d);
        *(half8*)(agg + (size_t)dst * 256 + col) = ov;
    }
}

// ---------------- d4: fused block-diag gemm0 + gemm1 + alpha1 ---------------
// Block = 32 rows; wave == head. Stage 1: hb[32][256] = relu(agg@W0h + b0)
// into LDS. Stage 2: xh = hb @ W11 (A from resident LDS), alpha1 epilogue.

__global__ __launch_bounds__(256) void fusedgemm_kernel(Args a) {
    __shared__ _Float16 hT[32][264];
    int half_ = (a.N / 32);
    int b = blockIdx.x;
    int s = (b >= half_);
    int bx = b - s * half_;
    int row0 = bx * 32;

    const _Float16* agg = s ? a.agg2 : a.agg1;
    const _Float16* Wt0 = s ? a.Wt20 : a.Wt10;
    const _Float16* Wt1 = s ? a.Wt21 : a.Wt11;
    const float* bias0  = s ? a.b20  : a.b10;
    const float* a_s    = s ? a.as21 : a.as11;
    const float* a_d    = s ? a.ad21 : a.ad11;
    _Float16* xh = s ? a.xh2 : a.xh1;
    float* alS = s ? a.alS2 : a.alS1;
    float* alD = s ? a.alD2 : a.alD1;

    int tid  = threadIdx.x;
    int wave = tid >> 6;          // == head
    int lane = tid & 63;
    int lo = lane & 15, hi = lane >> 4;
    int c0 = wave * 64;

    // ---- stage 1: block-diagonal gemm0 (M=32, N=64, K=64) ----
    {
        floatx4 acc[2][4] = {};
#pragma unroll
        for (int ks = 0; ks < 2; ks++) {
            half8 af[2], bf[4];
#pragma unroll
            for (int f = 0; f < 2; f++)
                af[f] = *(const half8*)(agg + (size_t)(row0 + f * 16 + lo) * 256
                                        + c0 + ks * 32 + hi * 8);
#pragma unroll
            for (int cf = 0; cf < 4; cf++)
                bf[cf] = *(const half8*)(Wt0 + (size_t)(c0 + cf * 16 + lo) * 64
                                         + ks * 32 + hi * 8);
#pragma unroll
            for (int f = 0; f < 2; f++)
#pragma unroll
                for (int cf = 0; cf < 4; cf++)
                    acc[f][cf] = __builtin_amdgcn_mfma_f32_16x16x32_f16(
                        af[f], bf[cf], acc[f][cf], 0, 0, 0);
        }
        float bb[4];
#pragma unroll
        for (int cf = 0; cf < 4; cf++) bb[cf] = bias0[c0 + cf * 16 + lo];
#pragma unroll
        for (int f = 0; f < 2; f++)
#pragma unroll
            for (int cf = 0; cf < 4; cf++)
#pragma unroll
                for (int r = 0; r < 4; r++) {
                    int row = f * 16 + hi * 4 + r;
                    float v = acc[f][cf][r] + bb[cf];
                    hT[row][c0 + cf * 16 + lo] = (_Float16)fmaxf(v, 0.f);
                }
    }
    __syncthreads();

    // ---- stage 2: gemm1 (M=32, N=64/wave, K=256), A resident in LDS ----
    floatx4 acc[2][4] = {};
#pragma unroll
    for (int ks = 0; ks < 8; ks++) {
        half8 af[2], bf[4];
#pragma unroll
        for (int f = 0; f < 2; f++)
            af[f] = *(const half8*)&hT[f * 16 + lo][ks * 32 + hi * 8];
#pragma unroll
        for (int cf = 0; cf < 4; cf++)
            bf[cf] = *(const half8*)(Wt1 + (size_t)(c0 + cf * 16 + lo) * 256
                                     + ks * 32 + hi * 8);
#pragma unroll
        for (int f = 0; f < 2; f++)
#pragma unroll
            for (int cf = 0; cf < 4; cf++)
                acc[f][cf] = __builtin_amdgcn_mfma_f32_16x16x32_f16(
                    af[f], bf[cf], acc[f][cf], 0, 0, 0);
    }

    float asw[4], adw[4];
#pragma unroll
    for (int cf = 0; cf < 4; cf++) {
        asw[cf] = a_s[c0 + cf * 16 + lo];
        adw[cf] = a_d[c0 + cf * 16 + lo];
    }
#pragma unroll
    for (int f = 0; f < 2; f++) {
#pragma unroll
        for (int r = 0; r < 4; r++) {
            int row = row0 + f * 16 + hi * 4 + r;
            float v0 = acc[f][0][r], v1 = acc[f][1][r];
            float v2 = acc[f][2][r], v3 = acc[f][3][r];
            _Float16* xrow = &xh[(size_t)row * 256 + c0 + lo];
            xrow[0]  = (_Float16)v0;
            xrow[16] = (_Float16)v1;
            xrow[32] = (_Float16)v2;
            xrow[48] = (_Float16)v3;
            float s1 = v0 * asw[0] + v1 * asw[1] + v2 * asw[2] + v3 * asw[3];
            float s2 = v0 * adw[0] + v1 * adw[1] + v2 * adw[2] + v3 * adw[3];
#pragma unroll
            for (int off = 1; off < 16; off <<= 1) {
                s1 += __shfl_xor(s1, off);
                s2 += __shfl_xor(s2, off);
            }
            if (lo == 0) {
                alS[row * 4 + wave] = s1;
                alD[row * 4 + wave] = s2;
            }
        }
    }
}

// ---------------- d5: attn1 (unchanged from R13) ----------------------------

__global__ __launch_bounds__(256) void attn1_kernel(Args a) {
    __shared__ float2 pairs[4][8][10];
    int tid = threadIdx.x;
    int h = tid >> 6, L = tid & 63, st = L >> 3, lc = L & 7;
    int b = blockIdx.x;
    int cpx = (2 * a.N) >> 3;
    int g = (b & 7) * cpx + (b >> 3);
    int s = (g >= a.N) ? 1 : 0;
    int dst = g - s * a.N;
    const _Float16* xh = s ? a.xh2  : a.xh1;
    const float* alS   = s ? a.alS2 : a.alS1;
    const float* alD   = s ? a.alD2 : a.alD1;
    const float* bias  = s ? a.b21  : a.b11;
    float* out         = s ? a.out1 : a.out0;

    const int* slots = a.slots + (size_t)g * ELLW;
    int pre = slots[L];
    int nd = a.cnt[g];
    if (nd > ELLW) nd = ELLW;
    float ad = alD[dst * 4 + h];
    const char* xb = (const char*)xh + h * 128 + lc * 16;

    float acc[8] = {};
    float pden = 0.f;

    for (int c = 0; c < nd; c += 64) {
        int n = nd - c; if (n > 64) n = 64;
        int off = 0; float p = 0.f;
        if (L < n) {
            int src = (c == 0) ? pre : slots[c + L];
            float t = alS[src * 4 + h] + ad;
            t = (t > 0.f) ? t : NEG_SLOPE * t;
            p = __expf(t);
            off = src * 512;
        }
        pden += p;
        pairs[h][L & 7][L >> 3] = make_float2(__int_as_float(off), p);
        int iters = (n + 7) >> 3;
        for (int ii = 0; ii < iters; ii += 4) {
            float4 twoA = *(const float4*)&pairs[h][st][ii];
            float4 twoB = *(const float4*)&pairs[h][st][ii + 2];
            int   o0 = __float_as_int(twoA.x); float w0 = twoA.y;
            int   o1i = __float_as_int(twoA.z); float w1 = twoA.w;
            int   o2i = __float_as_int(twoB.x); float w2 = twoB.y;
            int   o3i = __float_as_int(twoB.z); float w3 = twoB.w;
            float4 r0 = *(const float4*)(xb + o0);
            float4 r1 = *(const float4*)(xb + o1i);
            float4 r2 = *(const float4*)(xb + o2i);
            float4 r3 = *(const float4*)(xb + o3i);
            const __half2* q0 = (const __half2*)&r0;
            const __half2* q1 = (const __half2*)&r1;
            const __half2* q2 = (const __half2*)&r2;
            const __half2* q3 = (const __half2*)&r3;
#pragma unroll
            for (int k = 0; k < 4; k++) {
                acc[2 * k + 0] += (float)q0[k].x * w0;
                acc[2 * k + 1] += (float)q0[k].y * w0;
                acc[2 * k + 0] += (float)q1[k].x * w1;
                acc[2 * k + 1] += (float)q1[k].y * w1;
                acc[2 * k + 0] += (float)q2[k].x * w2;
                acc[2 * k + 1] += (float)q2[k].y * w2;
                acc[2 * k + 0] += (float)q3[k].x * w3;
                acc[2 * k + 1] += (float)q3[k].y * w3;
            }
        }
    }
#pragma unroll
    for (int k = 0; k < 8; k++) {
        acc[k] += __shfl_xor(acc[k], 8);
        acc[k] += __shfl_xor(acc[k], 16);
        acc[k] += __shfl_xor(acc[k], 32);
    }
#pragma unroll
    for (int o2_ = 32; o2_ >= 1; o2_ >>= 1) pden += __shfl_xor(pden, o2_);

    if (st == 0) {
        float d = 1.0f / (pden + 1e-16f);
        int col = h * 64 + lc * 8;
        float4 bA = *(const float4*)&bias[col];
        float4 bB = *(const float4*)&bias[col + 4];
        float4 oA, oB;
        oA.x = acc[0] * d + bA.x; oA.y = acc[1] * d + bA.y;
        oA.z = acc[2] * d + bA.z; oA.w = acc[3] * d + bA.w;
        oB.x = acc[4] * d + bB.x; oB.y = acc[5] * d + bB.y;
        oB.z = acc[6] * d + bB.z; oB.w = acc[7] * d + bB.w;
        *(float4*)&out[(size_t)dst * 256 + col] = oA;
        *(float4*)&out[(size_t)dst * 256 + col + 4] = oB;
    }
}

// ---------------------------------------------------------------------------

extern "C" void kernel_launch(void* const* d_in, const int* in_sizes, int n_in,
                              void* d_out, int out_size, void* d_ws, size_t ws_size,
                              hipStream_t stream) {
    const int N  = in_sizes[0] / 64;   // 8000 nodes
    const int E1 = in_sizes[1] / 2;
    const int E2 = in_sizes[2] / 2;

    char* base = (char*)d_ws;
    size_t off = 0;
    auto carve = [&](size_t bytes) -> void* {
        void* p = base + off;
        off += (bytes + 255) & ~(size_t)255;
        return p;
    };
    int* cnt        = (int*)carve((size_t)2 * N * 4);
    int* slots      = (int*)carve((size_t)2 * N * ELLW * 4);
    _Float16* agg1  = (_Float16*)carve((size_t)N * 256 * 2);
    _Float16* agg2  = (_Float16*)carve((size_t)N * 256 * 2);
    _Float16* xh1   = (_Float16*)carve((size_t)N * 256 * 2);
    _Float16* xh2   = (_Float16*)carve((size_t)N * 256 * 2);
    float* alS1     = (float*)carve((size_t)N * 4 * 4);
    float* alD1     = (float*)carve((size_t)N * 4 * 4);
    float* alS2     = (float*)carve((size_t)N * 4 * 4);
    float* alD2     = (float*)carve((size_t)N * 4 * 4);
    _Float16* Wt10  = (_Float16*)carve((size_t)256 * 64 * 2);
    _Float16* Wt20  = (_Float16*)carve((size_t)256 * 64 * 2);
    _Float16* Wt11  = (_Float16*)carve((size_t)256 * 256 * 2);
    _Float16* Wt21  = (_Float16*)carve((size_t)256 * 256 * 2);
    float* vaS1     = (float*)carve((size_t)256 * 4);
    float* vaD1     = (float*)carve((size_t)256 * 4);
    float* vaS2     = (float*)carve((size_t)256 * 4);
    float* vaD2     = (float*)carve((size_t)256 * 4);
    _Float16* h0h   = (_Float16*)carve((size_t)N * 64 * 2);
    (void)ws_size; (void)n_in;

    Args a;
    a.h0 = (const float*)d_in[0];
    a.ei1 = (const int*)d_in[1];
    a.ei2 = (const int*)d_in[2];
    a.W10 = (const float*)d_in[3];  a.as10 = (const float*)d_in[4];
    a.ad10 = (const float*)d_in[5]; a.b10 = (const float*)d_in[6];
    a.W11 = (const float*)d_in[7];  a.as11 = (const float*)d_in[8];
    a.ad11 = (const float*)d_in[9]; a.b11 = (const float*)d_in[10];
    a.W20 = (const float*)d_in[11]; a.as20 = (const float*)d_in[12];
    a.ad20 = (const float*)d_in[13]; a.b20 = (const float*)d_in[14];
    a.W21 = (const float*)d_in[15]; a.as21 = (const float*)d_in[16];
    a.ad21 = (const float*)d_in[17]; a.b21 = (const float*)d_in[18];
    a.Wt10 = Wt10; a.Wt20 = Wt20; a.Wt11 = Wt11; a.Wt21 = Wt21;
    a.vaS1 = vaS1; a.vaD1 = vaD1; a.vaS2 = vaS2; a.vaD2 = vaD2;
    a.h0h = h0h;
    a.cnt = cnt; a.slots = slots;
    a.agg1 = agg1; a.agg2 = agg2;
    a.xh1 = xh1; a.xh2 = xh2;
    a.alS1 = alS1; a.alD1 = alD1; a.alS2 = alS2; a.alD2 = alD2;
    a.out0 = (float*)d_out; a.out1 = (float*)d_out + (size_t)N * 256;
    a.N = N; a.E1 = E1; a.E2 = E2;
    a.AB = (2 * N + 3) / 4;

    int tot = (E1 + N) + (E2 + N);
    int scatterBlocks = (tot + 255) / 256;

    prep_kernel<<<dim3(256, 5, 2), 64, 0, stream>>>(a);
    scat_al0_kernel<<<a.AB + scatterBlocks, 256, 0, stream>>>(a);
    attn_agg_kernel<<<2 * N, 256, 0, stream>>>(a);
    fusedgemm_kernel<<<(N / 32) * 2, 256, 0, stream>>>(a);
    attn1_kernel<<<2 * N, 256, 0, stream>>>(a);
}

// Round 15
// 114.051 us; speedup vs baseline: 1.0531x; 1.0531x over previous
//
#include <hip/hip_runtime.h>
#include <hip/hip_fp16.h>

// ---------------------------------------------------------------------------
// MultiSourceGNNBlock: two independent 2-layer GAT stacks on shared input.
// R15: base = R14 (commute trick). Delta: XCD-PARTITIONED ELL scatter —
// 8 interleaved block groups (r = blockIdx&7 -> XCD r), each scans the full
// edge list but scatters only dst-range r (matching the attn swizzle's
// XCD->node-range map). All cnt atomics + slots writes become XCD-L2-local;
// kills the 42us random-write scatter bottleneck found in R14 counters.
// ---------------------------------------------------------------------------

#define NEG_SLOPE 0.2f
#define ELLW 96
#define EPT 8            // edges scanned per thread per group

typedef _Float16 half8 __attribute__((ext_vector_type(8)));
typedef float floatx4 __attribute__((ext_vector_type(4)));

struct Args {
    const float* h0;
    const int *ei1, *ei2;
    const float *W10, *W11, *W20, *W21;
    const float *as10, *ad10, *b10, *as11, *ad11, *b11;
    const float *as20, *ad20, *b20, *as21, *ad21, *b21;
    _Float16 *Wt10, *Wt20, *Wt11, *Wt21;    // W^T fp16
    float *vaS1, *vaD1, *vaS2, *vaD2;       // [4][64] = W0 @ a_{src,dst}
    _Float16 *h0h;                          // h0 as fp16 [N][64]
    int *cnt, *slots;
    _Float16 *agg1, *agg2;                  // [N][256] layer0 weighted sums
    _Float16 *xh1, *xh2;                    // [N][256] layer1 features
    float *alS1, *alD1, *alS2, *alD2;
    float *out0, *out1;
    int N, E1, E2, AB;                      // AB = al0 GEMV block count
};

// ---------------- d1: W transposes + va GEMV + h0->fp16 + cnt zero ----------

__global__ __launch_bounds__(64) void prep_kernel(Args a) {
    int z = blockIdx.z, y = blockIdx.y, c = blockIdx.x;
    int t = threadIdx.x;
    int flat = ((z * gridDim.y + y) * gridDim.x + c) * 64 + t;
    int GT = gridDim.x * gridDim.y * gridDim.z * 64;
    if (flat < 2 * a.N) a.cnt[flat] = 0;
    for (int i = flat; i < a.N * 64; i += GT)
        a.h0h[i] = (_Float16)a.h0[i];
    if (y == 0) {
        const float* W  = z ? a.W20  : a.W10;
        _Float16*    Wt = z ? a.Wt20 : a.Wt10;
        Wt[(size_t)c * 64 + t] = (_Float16)W[(size_t)t * 256 + c];
        if (c < 8) {
            int h = c & 3, sel = c >> 2;
            const float* av = sel ? (z ? a.ad20 : a.ad10)
                                  : (z ? a.as20 : a.as10);
            float* va = sel ? (z ? a.vaD2 : a.vaD1)
                            : (z ? a.vaS2 : a.vaS1);
            float acc = 0.f;
            for (int cc = 0; cc < 64; cc++)
                acc += W[(size_t)t * 256 + h * 64 + cc] * av[h * 64 + cc];
            va[h * 64 + t] = acc;
        }
    } else {
        int k = (y - 1) * 64 + t;
        const float* W  = z ? a.W21  : a.W11;
        _Float16*    Wt = z ? a.Wt21 : a.Wt11;
        Wt[(size_t)c * 256 + k] = (_Float16)W[(size_t)k * 256 + c];
    }
}

// ---------------- d2: alpha0 GEMV + XCD-partitioned ELL scatter -------------
// Blocks [0, AB): one wave per (source,node): alS0/alD0 = h0 . va.
// Blocks [AB, ...): group r = (b-AB)&7 scans all edges, scatters only
// g in [r*2N/8, (r+1)*2N/8) -> cnt/slots writes stay XCD-local.

__global__ __launch_bounds__(256) void scat_al0_kernel(Args a) {
    int b = blockIdx.x;
    int tid = threadIdx.x;
    if (b < a.AB) {
        int g = b * 4 + (tid >> 6);
        if (g >= 2 * a.N) return;
        int L = tid & 63;
        int s = (g >= a.N) ? 1 : 0;
        int i = g - s * a.N;
        const float* vaS = s ? a.vaS2 : a.vaS1;
        const float* vaD = s ? a.vaD2 : a.vaD1;
        float* alS = s ? a.alS2 : a.alS1;
        float* alD = s ? a.alD2 : a.alD1;
        float x = a.h0[(size_t)i * 64 + L];
#pragma unroll
        for (int h = 0; h < 4; h++) {
            float sv = x * vaS[h * 64 + L];
            float dv = x * vaD[h * 64 + L];
#pragma unroll
            for (int off = 32; off >= 1; off >>= 1) {
                sv += __shfl_xor(sv, off);
                dv += __shfl_xor(dv, off);
            }
            if (L == 0) {
                alS[i * 4 + h] = sv;
                alD[i * 4 + h] = dv;
            }
        }
    } else {
        int sb = b - a.AB;
        int r = sb & 7;                      // dst-range == XCD hint
        int chunk = sb >> 3;
        int cpx = (2 * a.N) >> 3;
        int glo = r * cpx, ghi = glo + cpx;
        int tot1 = a.E1 + a.N;
        int tot = tot1 + a.E2 + a.N;
        int base = chunk * (256 * EPT);
#pragma unroll
        for (int k = 0; k < EPT; k++) {
            int j = base + k * 256 + tid;
            if (j >= tot) break;
            int s, jj; const int* ei; int E;
            if (j < tot1) { s = 0; jj = j;        ei = a.ei1; E = a.E1; }
            else          { s = 1; jj = j - tot1; ei = a.ei2; E = a.E2; }
            int dst = (jj < E) ? ei[E + jj] : (jj - E);
            int gg = s * a.N + dst;
            if (gg < glo || gg >= ghi) continue;
            int src = (jj < E) ? ei[jj] : dst;
            int pos = atomicAdd(&a.cnt[gg], 1);
            if (pos < ELLW) a.slots[(size_t)gg * ELLW + pos] = src;
        }
    }
}

// ---------------- d3: attn0 in h0-space (8-stream ILP + XCD swizzle) --------

__global__ __launch_bounds__(256) void attn_agg_kernel(Args a) {
    __shared__ float2 pairs[4][8][10];
    int tid = threadIdx.x;
    int h = tid >> 6, L = tid & 63, st = L >> 3, lc = L & 7;
    int b = blockIdx.x;
    int cpx = (2 * a.N) >> 3;
    int g = (b & 7) * cpx + (b >> 3);
    int s = (g >= a.N) ? 1 : 0;
    int dst = g - s * a.N;
    const float* alS = s ? a.alS2 : a.alS1;
    const float* alD = s ? a.alD2 : a.alD1;
    _Float16*    agg = s ? a.agg2 : a.agg1;

    const int* slots = a.slots + (size_t)g * ELLW;
    int pre = slots[L];
    int nd = a.cnt[g];
    if (nd > ELLW) nd = ELLW;
    float ad = alD[dst * 4 + h];
    const char* xb = (const char*)a.h0h + lc * 16;

    float acc[8] = {};
    float pden = 0.f;

    for (int c = 0; c < nd; c += 64) {
        int n = nd - c; if (n > 64) n = 64;
        int off = 0; float p = 0.f;
        if (L < n) {
            int src = (c == 0) ? pre : slots[c + L];
            float t = alS[src * 4 + h] + ad;
            t = (t > 0.f) ? t : NEG_SLOPE * t;
            p = __expf(t);
            off = src * 128;
        }
        pden += p;
        pairs[h][L & 7][L >> 3] = make_float2(__int_as_float(off), p);
        int iters = (n + 7) >> 3;
        for (int ii = 0; ii < iters; ii += 4) {
            float4 twoA = *(const float4*)&pairs[h][st][ii];
            float4 twoB = *(const float4*)&pairs[h][st][ii + 2];
            int   o0 = __float_as_int(twoA.x); float w0 = twoA.y;
            int   o1i = __float_as_int(twoA.z); float w1 = twoA.w;
            int   o2i = __float_as_int(twoB.x); float w2 = twoB.y;
            int   o3i = __float_as_int(twoB.z); float w3 = twoB.w;
            float4 r0 = *(const float4*)(xb + o0);
            float4 r1 = *(const float4*)(xb + o1i);
            float4 r2 = *(const float4*)(xb + o2i);
            float4 r3 = *(const float4*)(xb + o3i);
            const __half2* q0 = (const __half2*)&r0;
            const __half2* q1 = (const __half2*)&r1;
            const __half2* q2 = (const __half2*)&r2;
            const __half2* q3 = (const __half2*)&r3;
#pragma unroll
            for (int k = 0; k < 4; k++) {
                acc[2 * k + 0] += (float)q0[k].x * w0;
                acc[2 * k + 1] += (float)q0[k].y * w0;
                acc[2 * k + 0] += (float)q1[k].x * w1;
                acc[2 * k + 1] += (float)q1[k].y * w1;
                acc[2 * k + 0] += (float)q2[k].x * w2;
                acc[2 * k + 1] += (float)q2[k].y * w2;
                acc[2 * k + 0] += (float)q3[k].x * w3;
                acc[2 * k + 1] += (float)q3[k].y * w3;
            }
        }
    }
#pragma unroll
    for (int k = 0; k < 8; k++) {
        acc[k] += __shfl_xor(acc[k], 8);
        acc[k] += __shfl_xor(acc[k], 16);
        acc[k] += __shfl_xor(acc[k], 32);
    }
#pragma unroll
    for (int o2_ = 32; o2_ >= 1; o2_ >>= 1) pden += __shfl_xor(pden, o2_);

    if (st == 0) {
        float d = 1.0f / (pden + 1e-16f);
        int col = h * 64 + lc * 8;
        half8 ov;
#pragma unroll
        for (int k = 0; k < 8; k++) ov[k] = (_Float16)(acc[k] * d);
        *(half8*)(agg + (size_t)dst * 256 + col) = ov;
    }
}

// ---------------- d4: fused block-diag gemm0 + gemm1 + alpha1 ---------------

__global__ __launch_bounds__(256) void fusedgemm_kernel(Args a) {
    __shared__ _Float16 hT[32][264];
    int half_ = (a.N / 32);
    int b = blockIdx.x;
    int s = (b >= half_);
    int bx = b - s * half_;
    int row0 = bx * 32;

    const _Float16* agg = s ? a.agg2 : a.agg1;
    const _Float16* Wt0 = s ? a.Wt20 : a.Wt10;
    const _Float16* Wt1 = s ? a.Wt21 : a.Wt11;
    const float* bias0  = s ? a.b20  : a.b10;
    const float* a_s    = s ? a.as21 : a.as11;
    const float* a_d    = s ? a.ad21 : a.ad11;
    _Float16* xh = s ? a.xh2 : a.xh1;
    float* alS = s ? a.alS2 : a.alS1;
    float* alD = s ? a.alD2 : a.alD1;

    int tid  = threadIdx.x;
    int wave = tid >> 6;
    int lane = tid & 63;
    int lo = lane & 15, hi = lane >> 4;
    int c0 = wave * 64;

    // ---- stage 1: block-diagonal gemm0 (M=32, N=64, K=64) ----
    {
        floatx4 acc[2][4] = {};
#pragma unroll
        for (int ks = 0; ks < 2; ks++) {
            half8 af[2], bf[4];
#pragma unroll
            for (int f = 0; f < 2; f++)
                af[f] = *(const half8*)(agg + (size_t)(row0 + f * 16 + lo) * 256
                                        + c0 + ks * 32 + hi * 8);
#pragma unroll
            for (int cf = 0; cf < 4; cf++)
                bf[cf] = *(const half8*)(Wt0 + (size_t)(c0 + cf * 16 + lo) * 64
                                         + ks * 32 + hi * 8);
#pragma unroll
            for (int f = 0; f < 2; f++)
#pragma unroll
                for (int cf = 0; cf < 4; cf++)
                    acc[f][cf] = __builtin_amdgcn_mfma_f32_16x16x32_f16(
                        af[f], bf[cf], acc[f][cf], 0, 0, 0);
        }
        float bb[4];
#pragma unroll
        for (int cf = 0; cf < 4; cf++) bb[cf] = bias0[c0 + cf * 16 + lo];
#pragma unroll
        for (int f = 0; f < 2; f++)
#pragma unroll
            for (int cf = 0; cf < 4; cf++)
#pragma unroll
                for (int r = 0; r < 4; r++) {
                    int row = f * 16 + hi * 4 + r;
                    float v = acc[f][cf][r] + bb[cf];
                    hT[row][c0 + cf * 16 + lo] = (_Float16)fmaxf(v, 0.f);
                }
    }
    __syncthreads();

    // ---- stage 2: gemm1 (M=32, K=256), A resident in LDS ----
    floatx4 acc[2][4] = {};
#pragma unroll
    for (int ks = 0; ks < 8; ks++) {
        half8 af[2], bf[4];
#pragma unroll
        for (int f = 0; f < 2; f++)
            af[f] = *(const half8*)&hT[f * 16 + lo][ks * 32 + hi * 8];
#pragma unroll
        for (int cf = 0; cf < 4; cf++)
            bf[cf] = *(const half8*)(Wt1 + (size_t)(c0 + cf * 16 + lo) * 256
                                     + ks * 32 + hi * 8);
#pragma unroll
        for (int f = 0; f < 2; f++)
#pragma unroll
            for (int cf = 0; cf < 4; cf++)
                acc[f][cf] = __builtin_amdgcn_mfma_f32_16x16x32_f16(
                    af[f], bf[cf], acc[f][cf], 0, 0, 0);
    }

    float asw[4], adw[4];
#pragma unroll
    for (int cf = 0; cf < 4; cf++) {
        asw[cf] = a_s[c0 + cf * 16 + lo];
        adw[cf] = a_d[c0 + cf * 16 + lo];
    }
#pragma unroll
    for (int f = 0; f < 2; f++) {
#pragma unroll
        for (int r = 0; r < 4; r++) {
            int row = row0 + f * 16 + hi * 4 + r;
            float v0 = acc[f][0][r], v1 = acc[f][1][r];
            float v2 = acc[f][2][r], v3 = acc[f][3][r];
            _Float16* xrow = &xh[(size_t)row * 256 + c0 + lo];
            xrow[0]  = (_Float16)v0;
            xrow[16] = (_Float16)v1;
            xrow[32] = (_Float16)v2;
            xrow[48] = (_Float16)v3;
            float s1 = v0 * asw[0] + v1 * asw[1] + v2 * asw[2] + v3 * asw[3];
            float s2 = v0 * adw[0] + v1 * adw[1] + v2 * adw[2] + v3 * adw[3];
#pragma unroll
            for (int off = 1; off < 16; off <<= 1) {
                s1 += __shfl_xor(s1, off);
                s2 += __shfl_xor(s2, off);
            }
            if (lo == 0) {
                alS[row * 4 + wave] = s1;
                alD[row * 4 + wave] = s2;
            }
        }
    }
}

// ---------------- d5: attn1 (xh-space, unchanged) ---------------------------

__global__ __launch_bounds__(256) void attn1_kernel(Args a) {
    __shared__ float2 pairs[4][8][10];
    int tid = threadIdx.x;
    int h = tid >> 6, L = tid & 63, st = L >> 3, lc = L & 7;
    int b = blockIdx.x;
    int cpx = (2 * a.N) >> 3;
    int g = (b & 7) * cpx + (b >> 3);
    int s = (g >= a.N) ? 1 : 0;
    int dst = g - s * a.N;
    const _Float16* xh = s ? a.xh2  : a.xh1;
    const float* alS   = s ? a.alS2 : a.alS1;
    const float* alD   = s ? a.alD2 : a.alD1;
    const float* bias  = s ? a.b21  : a.b11;
    float* out         = s ? a.out1 : a.out0;

    const int* slots = a.slots + (size_t)g * ELLW;
    int pre = slots[L];
    int nd = a.cnt[g];
    if (nd > ELLW) nd = ELLW;
    float ad = alD[dst * 4 + h];
    const char* xb = (const char*)xh + h * 128 + lc * 16;

    float acc[8] = {};
    float pden = 0.f;

    for (int c = 0; c < nd; c += 64) {
        int n = nd - c; if (n > 64) n = 64;
        int off = 0; float p = 0.f;
        if (L < n) {
            int src = (c == 0) ? pre : slots[c + L];
            float t = alS[src * 4 + h] + ad;
            t = (t > 0.f) ? t : NEG_SLOPE * t;
            p = __expf(t);
            off = src * 512;
        }
        pden += p;
        pairs[h][L & 7][L >> 3] = make_float2(__int_as_float(off), p);
        int iters = (n + 7) >> 3;
        for (int ii = 0; ii < iters; ii += 4) {
            float4 twoA = *(const float4*)&pairs[h][st][ii];
            float4 twoB = *(const float4*)&pairs[h][st][ii + 2];
            int   o0 = __float_as_int(twoA.x); float w0 = twoA.y;
            int   o1i = __float_as_int(twoA.z); float w1 = twoA.w;
            int   o2i = __float_as_int(twoB.x); float w2 = twoB.y;
            int   o3i = __float_as_int(twoB.z); float w3 = twoB.w;
            float4 r0 = *(const float4*)(xb + o0);
            float4 r1 = *(const float4*)(xb + o1i);
            float4 r2 = *(const float4*)(xb + o2i);
            float4 r3 = *(const float4*)(xb + o3i);
            const __half2* q0 = (const __half2*)&r0;
            const __half2* q1 = (const __half2*)&r1;
            const __half2* q2 = (const __half2*)&r2;
            const __half2* q3 = (const __half2*)&r3;
#pragma unroll
            for (int k = 0; k < 4; k++) {
                acc[2 * k + 0] += (float)q0[k].x * w0;
                acc[2 * k + 1] += (float)q0[k].y * w0;
                acc[2 * k + 0] += (float)q1[k].x * w1;
                acc[2 * k + 1] += (float)q1[k].y * w1;
                acc[2 * k + 0] += (float)q2[k].x * w2;
                acc[2 * k + 1] += (float)q2[k].y * w2;
                acc[2 * k + 0] += (float)q3[k].x * w3;
                acc[2 * k + 1] += (float)q3[k].y * w3;
            }
        }
    }
#pragma unroll
    for (int k = 0; k < 8; k++) {
        acc[k] += __shfl_xor(acc[k], 8);
        acc[k] += __shfl_xor(acc[k], 16);
        acc[k] += __shfl_xor(acc[k], 32);
    }
#pragma unroll
    for (int o2_ = 32; o2_ >= 1; o2_ >>= 1) pden += __shfl_xor(pden, o2_);

    if (st == 0) {
        float d = 1.0f / (pden + 1e-16f);
        int col = h * 64 + lc * 8;
        float4 bA = *(const float4*)&bias[col];
        float4 bB = *(const float4*)&bias[col + 4];
        float4 oA, oB;
        oA.x = acc[0] * d + bA.x; oA.y = acc[1] * d + bA.y;
        oA.z = acc[2] * d + bA.z; oA.w = acc[3] * d + bA.w;
        oB.x = acc[4] * d + bB.x; oB.y = acc[5] * d + bB.y;
        oB.z = acc[6] * d + bB.z; oB.w = acc[7] * d + bB.w;
        *(float4*)&out[(size_t)dst * 256 + col] = oA;
        *(float4*)&out[(size_t)dst * 256 + col + 4] = oB;
    }
}

// ---------------------------------------------------------------------------

extern "C" void kernel_launch(void* const* d_in, const int* in_sizes, int n_in,
                              void* d_out, int out_size, void* d_ws, size_t ws_size,
                              hipStream_t stream) {
    const int N  = in_sizes[0] / 64;   // 8000 nodes
    const int E1 = in_sizes[1] / 2;
    const int E2 = in_sizes[2] / 2;

    char* base = (char*)d_ws;
    size_t off = 0;
    auto carve = [&](size_t bytes) -> void* {
        void* p = base + off;
        off += (bytes + 255) & ~(size_t)255;
        return p;
    };
    int* cnt        = (int*)carve((size_t)2 * N * 4);
    int* slots      = (int*)carve((size_t)2 * N * ELLW * 4);
    _Float16* agg1  = (_Float16*)carve((size_t)N * 256 * 2);
    _Float16* agg2  = (_Float16*)carve((size_t)N * 256 * 2);
    _Float16* xh1   = (_Float16*)carve((size_t)N * 256 * 2);
    _Float16* xh2   = (_Float16*)carve((size_t)N * 256 * 2);
    float* alS1     = (float*)carve((size_t)N * 4 * 4);
    float* alD1     = (float*)carve((size_t)N * 4 * 4);
    float* alS2     = (float*)carve((size_t)N * 4 * 4);
    float* alD2     = (float*)carve((size_t)N * 4 * 4);
    _Float16* Wt10  = (_Float16*)carve((size_t)256 * 64 * 2);
    _Float16* Wt20  = (_Float16*)carve((size_t)256 * 64 * 2);
    _Float16* Wt11  = (_Float16*)carve((size_t)256 * 256 * 2);
    _Float16* Wt21  = (_Float16*)carve((size_t)256 * 256 * 2);
    float* vaS1     = (float*)carve((size_t)256 * 4);
    float* vaD1     = (float*)carve((size_t)256 * 4);
    float* vaS2     = (float*)carve((size_t)256 * 4);
    float* vaD2     = (float*)carve((size_t)256 * 4);
    _Float16* h0h   = (_Float16*)carve((size_t)N * 64 * 2);
    (void)ws_size; (void)n_in;

    Args a;
    a.h0 = (const float*)d_in[0];
    a.ei1 = (const int*)d_in[1];
    a.ei2 = (const int*)d_in[2];
    a.W10 = (const float*)d_in[3];  a.as10 = (const float*)d_in[4];
    a.ad10 = (const float*)d_in[5]; a.b10 = (const float*)d_in[6];
    a.W11 = (const float*)d_in[7];  a.as11 = (const float*)d_in[8];
    a.ad11 = (const float*)d_in[9]; a.b11 = (const float*)d_in[10];
    a.W20 = (const float*)d_in[11]; a.as20 = (const float*)d_in[12];
    a.ad20 = (const float*)d_in[13]; a.b20 = (const float*)d_in[14];
    a.W21 = (const float*)d_in[15]; a.as21 = (const float*)d_in[16];
    a.ad21 = (const float*)d_in[17]; a.b21 = (const float*)d_in[18];
    a.Wt10 = Wt10; a.Wt20 = Wt20; a.Wt11 = Wt11; a.Wt21 = Wt21;
    a.vaS1 = vaS1; a.vaD1 = vaD1; a.vaS2 = vaS2; a.vaD2 = vaD2;
    a.h0h = h0h;
    a.cnt = cnt; a.slots = slots;
    a.agg1 = agg1; a.agg2 = agg2;
    a.xh1 = xh1; a.xh2 = xh2;
    a.alS1 = alS1; a.alD1 = alD1; a.alS2 = alS2; a.alD2 = alD2;
    a.out0 = (float*)d_out; a.out1 = (float*)d_out + (size_t)N * 256;
    a.N = N; a.E1 = E1; a.E2 = E2;
    a.AB = (2 * N + 3) / 4;

    int tot = (E1 + N) + (E2 + N);
    int chunks = (tot + 256 * EPT - 1) / (256 * EPT);
    int scatterBlocks = chunks * 8;          // 8 dst-range groups, interleaved

    prep_kernel<<<dim3(256, 5, 2), 64, 0, stream>>>(a);
    scat_al0_kernel<<<a.AB + scatterBlocks, 256, 0, stream>>>(a);
    attn_agg_kernel<<<2 * N, 256, 0, stream>>>(a);
    fusedgemm_kernel<<<(N / 32) * 2, 256, 0, stream>>>(a);
    attn1_kernel<<<2 * N, 256, 0, stream>>>(a);
}

// Round 16
// 110.408 us; speedup vs baseline: 1.0878x; 1.0330x over previous
//
#include <hip/hip_runtime.h>
#include <hip/hip_fp16.h>

// ---------------------------------------------------------------------------
// MultiSourceGNNBlock: two independent 2-layer GAT stacks on shared input.
// R16: base = R15. Delta: prep + alpha0 + scatter merged into ONE dispatch
// (cnt zeroing via hipMemsetAsync; alpha0 re-blocked to 64 nodes/block with
// local va recompute in LDS -> no cross-block dependency). Pipeline:
// memset | mega_prep(prep∥alpha0∥scatter) | attn_agg | fusedgemm | attn1.
// ---------------------------------------------------------------------------

#define NEG_SLOPE 0.2f
#define ELLW 96
#define EPT 8            // edges scanned per thread per scatter group
#define NB_PREP 512      // grid-stride prep blocks (Wt transposes + h0h)

typedef _Float16 half8 __attribute__((ext_vector_type(8)));
typedef float floatx4 __attribute__((ext_vector_type(4)));

struct Args {
    const float* h0;
    const int *ei1, *ei2;
    const float *W10, *W11, *W20, *W21;
    const float *as10, *ad10, *b10, *as11, *ad11, *b11;
    const float *as20, *ad20, *b20, *as21, *ad21, *b21;
    _Float16 *Wt10, *Wt20, *Wt11, *Wt21;    // W^T fp16
    _Float16 *h0h;                          // h0 as fp16 [N][64]
    int *cnt, *slots;
    _Float16 *agg1, *agg2;                  // [N][256] layer0 weighted sums
    _Float16 *xh1, *xh2;                    // [N][256] layer1 features
    float *alS1, *alD1, *alS2, *alD2;
    float *out0, *out1;
    int N, E1, E2, AB;                      // AB = alpha0 block count (2N/64)
};

// ---------------- d1: mega prep — Wt/h0h ∥ alpha0 ∥ ELL scatter -------------
// Blocks [0, NB_PREP): grid-stride Wt transposes + h0h convert.
// Blocks [NB_PREP, NB_PREP+AB): alpha0 for 64 nodes, local va in LDS.
// Blocks [NB_PREP+AB, ...): XCD-partitioned edge scatter (r = sb&7).

__global__ __launch_bounds__(256) void mega_prep_kernel(Args a) {
    int b = blockIdx.x;
    int tid = threadIdx.x;

    if (b < NB_PREP) {
        int flat = b * 256 + tid;
        int GT = NB_PREP * 256;
        int totA = 32768;                  // layer0 Wt: 2 x 256x64
        int totB = totA + 131072;          // layer1 Wt: 2 x 256x256
        int totC = totB + a.N * 64;        // h0h convert
        for (int i = flat; i < totC; i += GT) {
            if (i < totA) {
                int s = i >> 14, rem = i & 16383;
                int c = rem >> 6, k = rem & 63;
                const float* W = s ? a.W20 : a.W10;
                _Float16* Wt = s ? a.Wt20 : a.Wt10;
                Wt[c * 64 + k] = (_Float16)W[k * 256 + c];
            } else if (i < totB) {
                int i2 = i - totA;
                int s = i2 >> 16, rem = i2 & 65535;
                int c = rem >> 8, k = rem & 255;
                const float* W = s ? a.W21 : a.W11;
                _Float16* Wt = s ? a.Wt21 : a.Wt11;
                Wt[c * 256 + k] = (_Float16)W[k * 256 + c];
            } else {
                int i3 = i - totB;
                a.h0h[i3] = (_Float16)a.h0[i3];
            }
        }
    } else if (b < NB_PREP + a.AB) {
        // ---- alpha0: 64 nodes, all in one source (64 | N) ----
        __shared__ float va[8][64];        // [sel*4+h][k]
        __shared__ float h0s[64][64];
        int ab = b - NB_PREP;
        int g0 = ab * 64;
        int s = (g0 >= a.N) ? 1 : 0;
        int i0 = g0 - s * a.N;
        const float* W0 = s ? a.W20 : a.W10;
        const float* aS = s ? a.as20 : a.as10;
        const float* aD = s ? a.ad20 : a.ad10;
        float* alS = s ? a.alS2 : a.alS1;
        float* alD = s ? a.alD2 : a.alD1;
        // va[sel*4+h][t] = sum_cc W0[t*256 + h*64+cc] * a{S,D}[h*64+cc]
#pragma unroll
        for (int o = 0; o < 2; o++) {
            int out = o * 256 + tid;       // 512 outputs
            int sel = out >> 8, rem = out & 255;
            int h = rem >> 6, t = rem & 63;
            const float* av = sel ? aD : aS;
            float acc = 0.f;
            const float* wrow = W0 + (size_t)t * 256 + h * 64;
            const float* arow = av + h * 64;
            for (int cc = 0; cc < 64; cc++) acc += wrow[cc] * arow[cc];
            va[sel * 4 + h][t] = acc;
        }
        // stage 64 h0 rows
#pragma unroll
        for (int e = 0; e < 16; e++) {
            int idx = e * 256 + tid;
            h0s[idx >> 6][idx & 63] = a.h0[(size_t)(i0 + (idx >> 6)) * 64 + (idx & 63)];
        }
        __syncthreads();
        // thread -> (node r = tid>>2, head h = tid&3): two 64-dim dots
        int r = tid >> 2, h = tid & 3;
        float sv = 0.f, dv = 0.f;
        for (int k = 0; k < 64; k++) {
            float x = h0s[r][k];
            sv += x * va[h][k];
            dv += x * va[4 + h][k];
        }
        alS[(i0 + r) * 4 + h] = sv;
        alD[(i0 + r) * 4 + h] = dv;
    } else {
        // ---- XCD-partitioned ELL scatter ----
        int sb = b - NB_PREP - a.AB;
        int rr = sb & 7;
        int chunk = sb >> 3;
        int cpx = (2 * a.N) >> 3;
        int glo = rr * cpx, ghi = glo + cpx;
        int tot1 = a.E1 + a.N;
        int tot = tot1 + a.E2 + a.N;
        int base = chunk * (256 * EPT);
#pragma unroll
        for (int k = 0; k < EPT; k++) {
            int j = base + k * 256 + tid;
            if (j >= tot) break;
            int s, jj; const int* ei; int E;
            if (j < tot1) { s = 0; jj = j;        ei = a.ei1; E = a.E1; }
            else          { s = 1; jj = j - tot1; ei = a.ei2; E = a.E2; }
            int dst = (jj < E) ? ei[E + jj] : (jj - E);
            int gg = s * a.N + dst;
            if (gg < glo || gg >= ghi) continue;
            int src = (jj < E) ? ei[jj] : dst;
            int pos = atomicAdd(&a.cnt[gg], 1);
            if (pos < ELLW) a.slots[(size_t)gg * ELLW + pos] = src;
        }
    }
}

// ---------------- d2: attn0 in h0-space (8-stream ILP + XCD swizzle) --------

__global__ __launch_bounds__(256) void attn_agg_kernel(Args a) {
    __shared__ float2 pairs[4][8][10];
    int tid = threadIdx.x;
    int h = tid >> 6, L = tid & 63, st = L >> 3, lc = L & 7;
    int b = blockIdx.x;
    int cpx = (2 * a.N) >> 3;
    int g = (b & 7) * cpx + (b >> 3);
    int s = (g >= a.N) ? 1 : 0;
    int dst = g - s * a.N;
    const float* alS = s ? a.alS2 : a.alS1;
    const float* alD = s ? a.alD2 : a.alD1;
    _Float16*    agg = s ? a.agg2 : a.agg1;

    const int* slots = a.slots + (size_t)g * ELLW;
    int pre = slots[L];
    int nd = a.cnt[g];
    if (nd > ELLW) nd = ELLW;
    float ad = alD[dst * 4 + h];
    const char* xb = (const char*)a.h0h + lc * 16;

    float acc[8] = {};
    float pden = 0.f;

    for (int c = 0; c < nd; c += 64) {
        int n = nd - c; if (n > 64) n = 64;
        int off = 0; float p = 0.f;
        if (L < n) {
            int src = (c == 0) ? pre : slots[c + L];
            float t = alS[src * 4 + h] + ad;
            t = (t > 0.f) ? t : NEG_SLOPE * t;
            p = __expf(t);
            off = src * 128;
        }
        pden += p;
        pairs[h][L & 7][L >> 3] = make_float2(__int_as_float(off), p);
        int iters = (n + 7) >> 3;
        for (int ii = 0; ii < iters; ii += 4) {
            float4 twoA = *(const float4*)&pairs[h][st][ii];
            float4 twoB = *(const float4*)&pairs[h][st][ii + 2];
            int   o0 = __float_as_int(twoA.x); float w0 = twoA.y;
            int   o1i = __float_as_int(twoA.z); float w1 = twoA.w;
            int   o2i = __float_as_int(twoB.x); float w2 = twoB.y;
            int   o3i = __float_as_int(twoB.z); float w3 = twoB.w;
            float4 r0 = *(const float4*)(xb + o0);
            float4 r1 = *(const float4*)(xb + o1i);
            float4 r2 = *(const float4*)(xb + o2i);
            float4 r3 = *(const float4*)(xb + o3i);
            const __half2* q0 = (const __half2*)&r0;
            const __half2* q1 = (const __half2*)&r1;
            const __half2* q2 = (const __half2*)&r2;
            const __half2* q3 = (const __half2*)&r3;
#pragma unroll
            for (int k = 0; k < 4; k++) {
                acc[2 * k + 0] += (float)q0[k].x * w0;
                acc[2 * k + 1] += (float)q0[k].y * w0;
                acc[2 * k + 0] += (float)q1[k].x * w1;
                acc[2 * k + 1] += (float)q1[k].y * w1;
                acc[2 * k + 0] += (float)q2[k].x * w2;
                acc[2 * k + 1] += (float)q2[k].y * w2;
                acc[2 * k + 0] += (float)q3[k].x * w3;
                acc[2 * k + 1] += (float)q3[k].y * w3;
            }
        }
    }
#pragma unroll
    for (int k = 0; k < 8; k++) {
        acc[k] += __shfl_xor(acc[k], 8);
        acc[k] += __shfl_xor(acc[k], 16);
        acc[k] += __shfl_xor(acc[k], 32);
    }
#pragma unroll
    for (int o2_ = 32; o2_ >= 1; o2_ >>= 1) pden += __shfl_xor(pden, o2_);

    if (st == 0) {
        float d = 1.0f / (pden + 1e-16f);
        int col = h * 64 + lc * 8;
        half8 ov;
#pragma unroll
        for (int k = 0; k < 8; k++) ov[k] = (_Float16)(acc[k] * d);
        *(half8*)(agg + (size_t)dst * 256 + col) = ov;
    }
}

// ---------------- d3: fused block-diag gemm0 + gemm1 + alpha1 ---------------

__global__ __launch_bounds__(256) void fusedgemm_kernel(Args a) {
    __shared__ _Float16 hT[32][264];
    int half_ = (a.N / 32);
    int b = blockIdx.x;
    int s = (b >= half_);
    int bx = b - s * half_;
    int row0 = bx * 32;

    const _Float16* agg = s ? a.agg2 : a.agg1;
    const _Float16* Wt0 = s ? a.Wt20 : a.Wt10;
    const _Float16* Wt1 = s ? a.Wt21 : a.Wt11;
    const float* bias0  = s ? a.b20  : a.b10;
    const float* a_s    = s ? a.as21 : a.as11;
    const float* a_d    = s ? a.ad21 : a.ad11;
    _Float16* xh = s ? a.xh2 : a.xh1;
    float* alS = s ? a.alS2 : a.alS1;
    float* alD = s ? a.alD2 : a.alD1;

    int tid  = threadIdx.x;
    int wave = tid >> 6;
    int lane = tid & 63;
    int lo = lane & 15, hi = lane >> 4;
    int c0 = wave * 64;

    // ---- stage 1: block-diagonal gemm0 (M=32, N=64, K=64) ----
    {
        floatx4 acc[2][4] = {};
#pragma unroll
        for (int ks = 0; ks < 2; ks++) {
            half8 af[2], bf[4];
#pragma unroll
            for (int f = 0; f < 2; f++)
                af[f] = *(const half8*)(agg + (size_t)(row0 + f * 16 + lo) * 256
                                        + c0 + ks * 32 + hi * 8);
#pragma unroll
            for (int cf = 0; cf < 4; cf++)
                bf[cf] = *(const half8*)(Wt0 + (size_t)(c0 + cf * 16 + lo) * 64
                                         + ks * 32 + hi * 8);
#pragma unroll
            for (int f = 0; f < 2; f++)
#pragma unroll
                for (int cf = 0; cf < 4; cf++)
                    acc[f][cf] = __builtin_amdgcn_mfma_f32_16x16x32_f16(
                        af[f], bf[cf], acc[f][cf], 0, 0, 0);
        }
        float bb[4];
#pragma unroll
        for (int cf = 0; cf < 4; cf++) bb[cf] = bias0[c0 + cf * 16 + lo];
#pragma unroll
        for (int f = 0; f < 2; f++)
#pragma unroll
            for (int cf = 0; cf < 4; cf++)
#pragma unroll
                for (int r = 0; r < 4; r++) {
                    int row = f * 16 + hi * 4 + r;
                    float v = acc[f][cf][r] + bb[cf];
                    hT[row][c0 + cf * 16 + lo] = (_Float16)fmaxf(v, 0.f);
                }
    }
    __syncthreads();

    // ---- stage 2: gemm1 (M=32, K=256), A resident in LDS ----
    floatx4 acc[2][4] = {};
#pragma unroll
    for (int ks = 0; ks < 8; ks++) {
        half8 af[2], bf[4];
#pragma unroll
        for (int f = 0; f < 2; f++)
            af[f] = *(const half8*)&hT[f * 16 + lo][ks * 32 + hi * 8];
#pragma unroll
        for (int cf = 0; cf < 4; cf++)
            bf[cf] = *(const half8*)(Wt1 + (size_t)(c0 + cf * 16 + lo) * 256
                                     + ks * 32 + hi * 8);
#pragma unroll
        for (int f = 0; f < 2; f++)
#pragma unroll
            for (int cf = 0; cf < 4; cf++)
                acc[f][cf] = __builtin_amdgcn_mfma_f32_16x16x32_f16(
                    af[f], bf[cf], acc[f][cf], 0, 0, 0);
    }

    float asw[4], adw[4];
#pragma unroll
    for (int cf = 0; cf < 4; cf++) {
        asw[cf] = a_s[c0 + cf * 16 + lo];
        adw[cf] = a_d[c0 + cf * 16 + lo];
    }
#pragma unroll
    for (int f = 0; f < 2; f++) {
#pragma unroll
        for (int r = 0; r < 4; r++) {
            int row = row0 + f * 16 + hi * 4 + r;
            float v0 = acc[f][0][r], v1 = acc[f][1][r];
            float v2 = acc[f][2][r], v3 = acc[f][3][r];
            _Float16* xrow = &xh[(size_t)row * 256 + c0 + lo];
            xrow[0]  = (_Float16)v0;
            xrow[16] = (_Float16)v1;
            xrow[32] = (_Float16)v2;
            xrow[48] = (_Float16)v3;
            float s1 = v0 * asw[0] + v1 * asw[1] + v2 * asw[2] + v3 * asw[3];
            float s2 = v0 * adw[0] + v1 * adw[1] + v2 * adw[2] + v3 * adw[3];
#pragma unroll
            for (int off = 1; off < 16; off <<= 1) {
                s1 += __shfl_xor(s1, off);
                s2 += __shfl_xor(s2, off);
            }
            if (lo == 0) {
                alS[row * 4 + wave] = s1;
                alD[row * 4 + wave] = s2;
            }
        }
    }
}

// ---------------- d4: attn1 (xh-space, unchanged) ---------------------------

__global__ __launch_bounds__(256) void attn1_kernel(Args a) {
    __shared__ float2 pairs[4][8][10];
    int tid = threadIdx.x;
    int h = tid >> 6, L = tid & 63, st = L >> 3, lc = L & 7;
    int b = blockIdx.x;
    int cpx = (2 * a.N) >> 3;
    int g = (b & 7) * cpx + (b >> 3);
    int s = (g >= a.N) ? 1 : 0;
    int dst = g - s * a.N;
    const _Float16* xh = s ? a.xh2  : a.xh1;
    const float* alS   = s ? a.alS2 : a.alS1;
    const float* alD   = s ? a.alD2 : a.alD1;
    const float* bias  = s ? a.b21  : a.b11;
    float* out         = s ? a.out1 : a.out0;

    const int* slots = a.slots + (size_t)g * ELLW;
    int pre = slots[L];
    int nd = a.cnt[g];
    if (nd > ELLW) nd = ELLW;
    float ad = alD[dst * 4 + h];
    const char* xb = (const char*)xh + h * 128 + lc * 16;

    float acc[8] = {};
    float pden = 0.f;

    for (int c = 0; c < nd; c += 64) {
        int n = nd - c; if (n > 64) n = 64;
        int off = 0; float p = 0.f;
        if (L < n) {
            int src = (c == 0) ? pre : slots[c + L];
            float t = alS[src * 4 + h] + ad;
            t = (t > 0.f) ? t : NEG_SLOPE * t;
            p = __expf(t);
            off = src * 512;
        }
        pden += p;
        pairs[h][L & 7][L >> 3] = make_float2(__int_as_float(off), p);
        int iters = (n + 7) >> 3;
        for (int ii = 0; ii < iters; ii += 4) {
            float4 twoA = *(const float4*)&pairs[h][st][ii];
            float4 twoB = *(const float4*)&pairs[h][st][ii + 2];
            int   o0 = __float_as_int(twoA.x); float w0 = twoA.y;
            int   o1i = __float_as_int(twoA.z); float w1 = twoA.w;
            int   o2i = __float_as_int(twoB.x); float w2 = twoB.y;
            int   o3i = __float_as_int(twoB.z); float w3 = twoB.w;
            float4 r0 = *(const float4*)(xb + o0);
            float4 r1 = *(const float4*)(xb + o1i);
            float4 r2 = *(const float4*)(xb + o2i);
            float4 r3 = *(const float4*)(xb + o3i);
            const __half2* q0 = (const __half2*)&r0;
            const __half2* q1 = (const __half2*)&r1;
            const __half2* q2 = (const __half2*)&r2;
            const __half2* q3 = (const __half2*)&r3;
#pragma unroll
            for (int k = 0; k < 4; k++) {
                acc[2 * k + 0] += (float)q0[k].x * w0;
                acc[2 * k + 1] += (float)q0[k].y * w0;
                acc[2 * k + 0] += (float)q1[k].x * w1;
                acc[2 * k + 1] += (float)q1[k].y * w1;
                acc[2 * k + 0] += (float)q2[k].x * w2;
                acc[2 * k + 1] += (float)q2[k].y * w2;
                acc[2 * k + 0] += (float)q3[k].x * w3;
                acc[2 * k + 1] += (float)q3[k].y * w3;
            }
        }
    }
#pragma unroll
    for (int k = 0; k < 8; k++) {
        acc[k] += __shfl_xor(acc[k], 8);
        acc[k] += __shfl_xor(acc[k], 16);
        acc[k] += __shfl_xor(acc[k], 32);
    }
#pragma unroll
    for (int o2_ = 32; o2_ >= 1; o2_ >>= 1) pden += __shfl_xor(pden, o2_);

    if (st == 0) {
        float d = 1.0f / (pden + 1e-16f);
        int col = h * 64 + lc * 8;
        float4 bA = *(const float4*)&bias[col];
        float4 bB = *(const float4*)&bias[col + 4];
        float4 oA, oB;
        oA.x = acc[0] * d + bA.x; oA.y = acc[1] * d + bA.y;
        oA.z = acc[2] * d + bA.z; oA.w = acc[3] * d + bA.w;
        oB.x = acc[4] * d + bB.x; oB.y = acc[5] * d + bB.y;
        oB.z = acc[6] * d + bB.z; oB.w = acc[7] * d + bB.w;
        *(float4*)&out[(size_t)dst * 256 + col] = oA;
        *(float4*)&out[(size_t)dst * 256 + col + 4] = oB;
    }
}

// ---------------------------------------------------------------------------

extern "C" void kernel_launch(void* const* d_in, const int* in_sizes, int n_in,
                              void* d_out, int out_size, void* d_ws, size_t ws_size,
                              hipStream_t stream) {
    const int N  = in_sizes[0] / 64;   // 8000 nodes
    const int E1 = in_sizes[1] / 2;
    const int E2 = in_sizes[2] / 2;

    char* base = (char*)d_ws;
    size_t off = 0;
    auto carve = [&](size_t bytes) -> void* {
        void* p = base + off;
        off += (bytes + 255) & ~(size_t)255;
        return p;
    };
    int* cnt        = (int*)carve((size_t)2 * N * 4);
    int* slots      = (int*)carve((size_t)2 * N * ELLW * 4);
    _Float16* agg1  = (_Float16*)carve((size_t)N * 256 * 2);
    _Float16* agg2  = (_Float16*)carve((size_t)N * 256 * 2);
    _Float16* xh1   = (_Float16*)carve((size_t)N * 256 * 2);
    _Float16* xh2   = (_Float16*)carve((size_t)N * 256 * 2);
    float* alS1     = (float*)carve((size_t)N * 4 * 4);
    float* alD1     = (float*)carve((size_t)N * 4 * 4);
    float* alS2     = (float*)carve((size_t)N * 4 * 4);
    float* alD2     = (float*)carve((size_t)N * 4 * 4);
    _Float16* Wt10  = (_Float16*)carve((size_t)256 * 64 * 2);
    _Float16* Wt20  = (_Float16*)carve((size_t)256 * 64 * 2);
    _Float16* Wt11  = (_Float16*)carve((size_t)256 * 256 * 2);
    _Float16* Wt21  = (_Float16*)carve((size_t)256 * 256 * 2);
    _Float16* h0h   = (_Float16*)carve((size_t)N * 64 * 2);
    (void)ws_size; (void)n_in;

    Args a;
    a.h0 = (const float*)d_in[0];
    a.ei1 = (const int*)d_in[1];
    a.ei2 = (const int*)d_in[2];
    a.W10 = (const float*)d_in[3];  a.as10 = (const float*)d_in[4];
    a.ad10 = (const float*)d_in[5]; a.b10 = (const float*)d_in[6];
    a.W11 = (const float*)d_in[7];  a.as11 = (const float*)d_in[8];
    a.ad11 = (const float*)d_in[9]; a.b11 = (const float*)d_in[10];
    a.W20 = (const float*)d_in[11]; a.as20 = (const float*)d_in[12];
    a.ad20 = (const float*)d_in[13]; a.b20 = (const float*)d_in[14];
    a.W21 = (const float*)d_in[15]; a.as21 = (const float*)d_in[16];
    a.ad21 = (const float*)d_in[17]; a.b21 = (const float*)d_in[18];
    a.Wt10 = Wt10; a.Wt20 = Wt20; a.Wt11 = Wt11; a.Wt21 = Wt21;
    a.h0h = h0h;
    a.cnt = cnt; a.slots = slots;
    a.agg1 = agg1; a.agg2 = agg2;
    a.xh1 = xh1; a.xh2 = xh2;
    a.alS1 = alS1; a.alD1 = alD1; a.alS2 = alS2; a.alD2 = alD2;
    a.out0 = (float*)d_out; a.out1 = (float*)d_out + (size_t)N * 256;
    a.N = N; a.E1 = E1; a.E2 = E2;
    a.AB = (2 * N) / 64;               // 250 alpha0 blocks

    int tot = (E1 + N) + (E2 + N);
    int chunks = (tot + 256 * EPT - 1) / (256 * EPT);
    int scatterBlocks = chunks * 8;

    hipMemsetAsync(cnt, 0, (size_t)2 * N * 4, stream);
    mega_prep_kernel<<<NB_PREP + a.AB + scatterBlocks, 256, 0, stream>>>(a);
    attn_agg_kernel<<<2 * N, 256, 0, stream>>>(a);
    fusedgemm_kernel<<<(N / 32) * 2, 256, 0, stream>>>(a);
    attn1_kernel<<<2 * N, 256, 0, stream>>>(a);
}